// Round 8
// baseline (309.464 us; speedup 1.0000x reference)
//
#include <hip/hip_runtime.h>
#include <hip/hip_bf16.h>
#include <cstdint>
#include <type_traits>

// SingleHeadAttention. Numerics (validated r2-r7, absmax 1.0):
//   Q/K proj: 3-term split-bf16 MFMA; Q,K quantized int16-fixed (q=a*256+b);
//   S = (H<<16+M<<8+L)*2^-21 exact -> fp32 (i16-S clamps! r6); V/P/PV bf16.
// r8: PV restructure (was the top dispatch, 83us, MfmaUtil 15%, FETCH 135MB):
//   - BK=64 elems (128B LDS rows, XOR-swizzled chunks, s_i8's r6 pattern):
//     32 MFMA/iter/wave, half the barrier drains.
//   - grid x=bm: XCD (linear id % 8) = bm%8 -> P tiles + O atomics stay in
//     one XCD's L2 (P was re-fetched ~4x across XCDs with x=bn).
//   - split-K 2->4: 1024 blocks = 4/CU, overlaps remaining barrier drains.

using u16 = unsigned short;
typedef __attribute__((ext_vector_type(8))) short short8;
typedef __attribute__((ext_vector_type(4))) float floatx4;
typedef __attribute__((ext_vector_type(4))) int intx4;

static constexpr int S_SEQ = 4096;
static constexpr int D_IN  = 1024;
static constexpr int D_OUT = 1024;

__device__ __forceinline__ u16 f2b(float f) {
  uint32_t u = __builtin_bit_cast(uint32_t, f);
  u = (u + 0x7FFFu + ((u >> 16) & 1u)) >> 16;
  return (u16)u;
}
__device__ __forceinline__ float b2f(u16 b) {
  return __builtin_bit_cast(float, (uint32_t)b << 16);
}
__device__ __forceinline__ void load16(const void* g, void* l) {
  __builtin_amdgcn_global_load_lds(
      (const __attribute__((address_space(1))) void*)g,
      (__attribute__((address_space(3))) void*)l,
      16, 0, 0);
}

// ---------------- conversions ----------------

__global__ void split_bf16_kernel(const float* __restrict__ in,
                                  u16* __restrict__ hi, u16* __restrict__ lo,
                                  int n4) {
  int i = blockIdx.x * blockDim.x + threadIdx.x;
  if (i >= n4) return;
  float4 v = reinterpret_cast<const float4*>(in)[i];
  ushort4 h, l;
  h.x = f2b(v.x); l.x = f2b(v.x - b2f(h.x));
  h.y = f2b(v.y); l.y = f2b(v.y - b2f(h.y));
  h.z = f2b(v.z); l.z = f2b(v.z - b2f(h.z));
  h.w = f2b(v.w); l.w = f2b(v.w - b2f(h.w));
  reinterpret_cast<ushort4*>(hi)[i] = h;
  reinterpret_cast<ushort4*>(lo)[i] = l;
}

// z=0:Wq z=1:Wk (split H+L), z=2:Wv (H only). WtH[3072][1024], WtL[2048][1024]
__global__ void transpose_w_kernel(const float* __restrict__ Wq,
                                   const float* __restrict__ Wk,
                                   const float* __restrict__ Wv,
                                   u16* __restrict__ WtH, u16* __restrict__ WtL) {
  const int z = blockIdx.z;
  const float* src = (z == 0) ? Wq : (z == 1) ? Wk : Wv;
  u16* dH = WtH + (size_t)z * 1024 * 1024;
  u16* dL = (z < 2) ? WtL + (size_t)z * 1024 * 1024 : nullptr;
  __shared__ float tile[32][33];
  int bx = blockIdx.x * 32, by = blockIdx.y * 32;
  int tx = threadIdx.x, ty = threadIdx.y;   // block (32,8)
  for (int j = 0; j < 32; j += 8)
    tile[ty + j][tx] = src[(size_t)(by + ty + j) * 1024 + bx + tx];
  __syncthreads();
  for (int j = 0; j < 32; j += 8) {
    float v = tile[tx][ty + j];
    u16 h = f2b(v);
    size_t idx = (size_t)(bx + ty + j) * 1024 + by + tx;
    dH[idx] = h;
    if (dL) dL[idx] = f2b(v - b2f(h));
  }
}

// ---------------- merged QKV projection (split-bf16 compute) ----------------
__global__ __launch_bounds__(256)
void qkv_kernel(const u16* __restrict__ Xh, const u16* __restrict__ Xl,
                const u16* __restrict__ WtH, const u16* __restrict__ WtL,
                char* __restrict__ Qa, char* __restrict__ Qb,
                char* __restrict__ Ka, char* __restrict__ Kb,
                u16* __restrict__ Vt) {
  constexpr int BK = 32, K = D_IN;
  constexpr int TILE = 128 * BK;
  __shared__ __align__(16) u16 smem[4 * TILE];
  u16* AsH = smem;
  u16* BsH = smem + TILE;
  u16* AsL = smem + 2 * TILE;
  u16* BsL = smem + 3 * TILE;

  const int tid  = threadIdx.x;
  const int wave = tid >> 6;
  const int lane = tid & 63;
  const int bm   = blockIdx.y * 128;
  const int bn   = blockIdx.x * 128;     // [0,3072)
  const bool splitB = bn < 2048;
  const int wm   = (wave >> 1) * 64;
  const int wn   = (wave & 1) * 64;
  const int quad = lane >> 4;
  const int l16  = lane & 15;

  const int srow = wave * 16 + (lane >> 2);
  const int scol = (lane & 3) * 8;
  const size_t offA = (size_t)(bm + srow) * K + scol;
  const size_t offB = (size_t)(bn + srow) * K + scol;
  const size_t off64 = (size_t)64 * K;
  const int lds0 = wave * 512;
  const int lds1 = 2048 + wave * 512;

  floatx4 acc[4][4] = {};

  for (int k0 = 0; k0 < K; k0 += BK) {
    __syncthreads();
    load16(Xh + offA + k0,          AsH + lds0);
    load16(Xh + offA + off64 + k0,  AsH + lds1);
    load16(WtH + offB + k0,         BsH + lds0);
    load16(WtH + offB + off64 + k0, BsH + lds1);
    if (splitB) {
      load16(Xl + offA + k0,          AsL + lds0);
      load16(Xl + offA + off64 + k0,  AsL + lds1);
      load16(WtL + offB + k0,         BsL + lds0);
      load16(WtL + offB + off64 + k0, BsL + lds1);
    }
    __syncthreads();

    short8 ah[4], bh[4], al[4], bl[4];
#pragma unroll
    for (int t = 0; t < 4; ++t) {
      ah[t] = *reinterpret_cast<const short8*>(AsH + (wm + t * 16 + l16) * BK + quad * 8);
      bh[t] = *reinterpret_cast<const short8*>(BsH + (wn + t * 16 + l16) * BK + quad * 8);
    }
    if (splitB) {
#pragma unroll
      for (int t = 0; t < 4; ++t) {
        al[t] = *reinterpret_cast<const short8*>(AsL + (wm + t * 16 + l16) * BK + quad * 8);
        bl[t] = *reinterpret_cast<const short8*>(BsL + (wn + t * 16 + l16) * BK + quad * 8);
      }
    }

#pragma unroll
    for (int mt = 0; mt < 4; ++mt)
#pragma unroll
      for (int nt = 0; nt < 4; ++nt)
        acc[mt][nt] = __builtin_amdgcn_mfma_f32_16x16x32_bf16(
            ah[mt], bh[nt], acc[mt][nt], 0, 0, 0);
    if (splitB) {
#pragma unroll
      for (int mt = 0; mt < 4; ++mt)
#pragma unroll
        for (int nt = 0; nt < 4; ++nt) {
          acc[mt][nt] = __builtin_amdgcn_mfma_f32_16x16x32_bf16(
              ah[mt], bl[nt], acc[mt][nt], 0, 0, 0);
          acc[mt][nt] = __builtin_amdgcn_mfma_f32_16x16x32_bf16(
              al[mt], bh[nt], acc[mt][nt], 0, 0, 0);
        }
    }
  }

  // epilogue (C/D: col=lane&15, row=quad*4+reg)
#pragma unroll
  for (int mt = 0; mt < 4; ++mt) {
#pragma unroll
    for (int nt = 0; nt < 4; ++nt) {
      const int row = bm + wm + mt * 16 + quad * 4;
      const int col = bn + wn + nt * 16 + l16;
      if (bn < 2048) {                 // Q or K -> int16-fixed byte planes
        char* Pa = (bn < 1024) ? Qa : Ka;
        char* Pb = (bn < 1024) ? Qb : Kb;
        const int c = (bn < 1024) ? col : col - 1024;
#pragma unroll
        for (int r = 0; r < 4; ++r) {
          float v = acc[mt][nt][r];
          int q16 = (int)rintf(v * 256.f);
          q16 = min(max(q16, -32512), 32512);    // |Q| <= 127 (6.9 sigma)
          int a = (q16 + 128) >> 8;              // a in [-127,127]
          int b = q16 - (a << 8);                // b in [-128,127]
          size_t idx = (size_t)(row + r) * 1024 + c;
          Pa[idx] = (char)a;
          Pb[idx] = (char)b;
        }
      } else {                         // V, write transposed, packed 8B store
        ushort4 o;
        o.x = f2b(acc[mt][nt][0]);
        o.y = f2b(acc[mt][nt][1]);
        o.z = f2b(acc[mt][nt][2]);
        o.w = f2b(acc[mt][nt][3]);
        *reinterpret_cast<ushort4*>(Vt + (size_t)(col - 2048) * S_SEQ + row) = o;
      }
    }
  }
}

// ---------------- i8 fixed-point S GEMM ----------------
// S[m][n] = (H<<16 + M<<8 + L) * 2^-21  (fp32; exact int recombine)
// Tile 128x64, BK=128 bytes, 8 iters. LDS rows 128B = 8 chunks of 16B;
// chunk g of row R stored at slot g^(R&7) -> conflict-free b128 frag reads.
__global__ __launch_bounds__(256)
void s_i8_kernel(const char* __restrict__ Qa, const char* __restrict__ Qb,
                 const char* __restrict__ Ka, const char* __restrict__ Kb,
                 float* __restrict__ S) {
  constexpr int K = D_IN, BK = 128;
  __shared__ __align__(16) char smem[48 * 1024];
  char* QaS = smem;                // [128][128]
  char* QbS = smem + 16384;        // [128][128]
  char* KaS = smem + 32768;        // [64][128]
  char* KbS = smem + 40960;        // [64][128]

  const int tid  = threadIdx.x;
  const int wave = tid >> 6;
  const int lane = tid & 63;
  const int bm   = blockIdx.y * 128;
  const int bn   = blockIdx.x * 64;
  const int wm   = (wave >> 1) * 64;
  const int wn   = (wave & 1) * 32;
  const int quad = lane >> 4;
  const int l16  = lane & 15;

  // staging: 8 rows x 128B per wave-issue; lane -> (row=srow, chunk=(lane&7)^srow)
  const int srow = lane >> 3;                 // 0..7
  const int scol = ((lane & 7) ^ srow) * 16;  // XOR swizzle
  int gQ[4], gK[2];
#pragma unroll
  for (int j = 0; j < 4; ++j)
    gQ[j] = (bm + j * 32 + wave * 8 + srow) * K + scol;
#pragma unroll
  for (int j = 0; j < 2; ++j)
    gK[j] = (bn + j * 32 + wave * 8 + srow) * K + scol;
  const int lQ[4] = {(0 * 32 + wave * 8) * 128, (1 * 32 + wave * 8) * 128,
                     (2 * 32 + wave * 8) * 128, (3 * 32 + wave * 8) * 128};
  const int lK[2] = {(0 * 32 + wave * 8) * 128, (1 * 32 + wave * 8) * 128};

  // frag reads: row R, global chunk g=quad+4s at slot (g^(R&7))
  const int r7 = l16 & 7;
  int cA[4], cB[2];
#pragma unroll
  for (int t = 0; t < 4; ++t)
    cA[t] = (wm + t * 16 + l16) * 128 + ((quad ^ r7) * 16);
#pragma unroll
  for (int t = 0; t < 2; ++t)
    cB[t] = (wn + t * 16 + l16) * 128 + ((quad ^ r7) * 16);

  intx4 accH[4][2] = {};
  intx4 accM[4][2] = {};
  intx4 accL[4][2] = {};

  for (int k0 = 0; k0 < K; k0 += BK) {
    __syncthreads();
#pragma unroll
    for (int j = 0; j < 4; ++j) {
      load16(Qa + gQ[j] + k0, QaS + lQ[j]);
      load16(Qb + gQ[j] + k0, QbS + lQ[j]);
    }
#pragma unroll
    for (int j = 0; j < 2; ++j) {
      load16(Ka + gK[j] + k0, KaS + lK[j]);
      load16(Kb + gK[j] + k0, KbS + lK[j]);
    }
    __syncthreads();

#pragma unroll
    for (int s = 0; s < 2; ++s) {
      const int so = s * 64;
      intx4 ah[4], al[4];
#pragma unroll
      for (int t = 0; t < 4; ++t) {
        ah[t] = *reinterpret_cast<const intx4*>(QaS + (cA[t] ^ so));
        al[t] = *reinterpret_cast<const intx4*>(QbS + (cA[t] ^ so));
      }
#pragma unroll
      for (int nt = 0; nt < 2; ++nt) {
        intx4 bh = *reinterpret_cast<const intx4*>(KaS + (cB[nt] ^ so));
#pragma unroll
        for (int mt = 0; mt < 4; ++mt) {
          accH[mt][nt] = __builtin_amdgcn_mfma_i32_16x16x64_i8(ah[mt], bh, accH[mt][nt], 0, 0, 0);
          accM[mt][nt] = __builtin_amdgcn_mfma_i32_16x16x64_i8(al[mt], bh, accM[mt][nt], 0, 0, 0);
        }
        intx4 bl = *reinterpret_cast<const intx4*>(KbS + (cB[nt] ^ so));
#pragma unroll
        for (int mt = 0; mt < 4; ++mt) {
          accM[mt][nt] = __builtin_amdgcn_mfma_i32_16x16x64_i8(ah[mt], bl, accM[mt][nt], 0, 0, 0);
          accL[mt][nt] = __builtin_amdgcn_mfma_i32_16x16x64_i8(al[mt], bl, accL[mt][nt], 0, 0, 0);
        }
      }
    }
  }

  // epilogue: exact int64 recombine -> fp32, scale 2^-16 (fixed^2) * 2^-5 (1/32)
  constexpr float SC = 4.76837158203125e-07f;
#pragma unroll
  for (int mt = 0; mt < 4; ++mt)
#pragma unroll
    for (int nt = 0; nt < 2; ++nt) {
      const int row = bm + wm + mt * 16 + quad * 4;
      const int col = bn + wn + nt * 16 + l16;
#pragma unroll
      for (int r = 0; r < 4; ++r) {
        long long fix = (((long long)accH[mt][nt][r]) << 16) +
                        (((long long)accM[mt][nt][r]) << 8) +
                        (long long)accL[mt][nt][r];
        S[(size_t)(row + r) * S_SEQ + col] = (float)fix * SC;
      }
    }
}

// ---------------- PV GEMM: O += P(bf16) . V, split-K4, atomic ----------------
// Tile 128x128, BK=64 elems (128B LDS rows, chunk g of row R at slot g^(R&7)).
// Grid (x=bm 32, y=bn 8, z=ksplit 4): XCD = id%8 = bm%8 -> P tiles and O
// atomics stay in one XCD's L2 across all bn and z.
__global__ __launch_bounds__(256)
void pv_kernel(const u16* __restrict__ P, const u16* __restrict__ Vt,
               float* __restrict__ O) {
  constexpr int LDA = S_SEQ;          // row stride of P and Vt (elements)
  constexpr int KS  = S_SEQ / 4;      // 1024 per z-slice
  constexpr int BK  = 64;
  __shared__ __align__(16) u16 smem[2 * 128 * 64];   // 32 KB
  u16* As = smem;                     // P tile   [128][64] swizzled
  u16* Bs = smem + 128 * 64;          // Vt tile  [128][64] swizzled

  const int tid  = threadIdx.x;
  const int wave = tid >> 6;
  const int lane = tid & 63;
  const int bm   = blockIdx.x * 128;
  const int bn   = blockIdx.y * 128;
  const int kz   = blockIdx.z * KS;
  const int wm   = (wave >> 1) * 64;
  const int wn   = (wave & 1) * 64;
  const int quad = lane >> 4;
  const int l16  = lane & 15;

  // staging: 8 rows x 128B per issue; lane -> (row=srow, chunk=(lane&7)^srow)
  const int srow  = lane >> 3;
  const int selem = ((lane & 7) ^ srow) * 8;     // element offset within row
  size_t gA[4], gB[4];
#pragma unroll
  for (int j = 0; j < 4; ++j) {
    gA[j] = (size_t)(bm + j * 32 + wave * 8 + srow) * LDA + kz + selem;
    gB[j] = (size_t)(bn + j * 32 + wave * 8 + srow) * LDA + kz + selem;
  }
  const int lds[4] = {(wave * 8 + 0) * 64, (wave * 8 + 32) * 64,
                      (wave * 8 + 64) * 64, (wave * 8 + 96) * 64};

  // frag reads: row R, k-chunk g=quad+4s (8 elems) at slot g^(R&7)
  int cA[4], cB[4];
#pragma unroll
  for (int t = 0; t < 4; ++t) {
    const int Ra = wm + t * 16 + l16;
    const int Rb = wn + t * 16 + l16;
    cA[t] = Ra * 64 + ((quad ^ (Ra & 7)) * 8);
    cB[t] = Rb * 64 + ((quad ^ (Rb & 7)) * 8);
  }

  floatx4 acc[4][4] = {};

  for (int k0 = 0; k0 < KS; k0 += BK) {
    __syncthreads();
#pragma unroll
    for (int j = 0; j < 4; ++j) {
      load16(P + gA[j] + k0,  As + lds[j]);
      load16(Vt + gB[j] + k0, Bs + lds[j]);
    }
    __syncthreads();

#pragma unroll
    for (int s = 0; s < 2; ++s) {
      const int so = s * 32;              // flips slot bit 2 (u16 units)
      short8 af[4], bf[4];
#pragma unroll
      for (int t = 0; t < 4; ++t) {
        af[t] = *reinterpret_cast<const short8*>(As + (cA[t] ^ so));
        bf[t] = *reinterpret_cast<const short8*>(Bs + (cB[t] ^ so));
      }
#pragma unroll
      for (int mt = 0; mt < 4; ++mt)
#pragma unroll
        for (int nt = 0; nt < 4; ++nt)
          acc[mt][nt] = __builtin_amdgcn_mfma_f32_16x16x32_bf16(
              af[mt], bf[nt], acc[mt][nt], 0, 0, 0);
    }
  }

#pragma unroll
  for (int mt = 0; mt < 4; ++mt)
#pragma unroll
    for (int nt = 0; nt < 4; ++nt) {
      const int row = bm + wm + mt * 16 + quad * 4;
      const int col = bn + wn + nt * 16 + l16;
#pragma unroll
      for (int r = 0; r < 4; ++r)
        atomicAdd(&O[(size_t)(row + r) * D_OUT + col], acc[mt][nt][r]);
    }
}

// ---------------- single-pass softmax (block per row, fp32 input) ----------
__global__ __launch_bounds__(256)
void softmax_kernel(const float* __restrict__ S, u16* __restrict__ P) {
  const int row = blockIdx.x, tid = threadIdx.x;
  const int lane = tid & 63, wave = tid >> 6;
  __shared__ float red[4];
  const float4* src = reinterpret_cast<const float4*>(S + (size_t)row * S_SEQ);
  ushort4* dst = reinterpret_cast<ushort4*>(P + (size_t)row * S_SEQ);

  float4 v[4];
  float m = -INFINITY;
#pragma unroll
  for (int t = 0; t < 4; ++t) {
    v[t] = src[tid + t * 256];
    m = fmaxf(m, fmaxf(fmaxf(v[t].x, v[t].y), fmaxf(v[t].z, v[t].w)));
  }
#pragma unroll
  for (int off = 1; off < 64; off <<= 1) m = fmaxf(m, __shfl_xor(m, off));
  if (lane == 0) red[wave] = m;
  __syncthreads();
  m = fmaxf(fmaxf(red[0], red[1]), fmaxf(red[2], red[3]));

  float e[16];
  float l = 0.f;
#pragma unroll
  for (int t = 0; t < 4; ++t) {
    e[4 * t + 0] = __expf(v[t].x - m);
    e[4 * t + 1] = __expf(v[t].y - m);
    e[4 * t + 2] = __expf(v[t].z - m);
    e[4 * t + 3] = __expf(v[t].w - m);
    l += e[4 * t + 0] + e[4 * t + 1] + e[4 * t + 2] + e[4 * t + 3];
  }
#pragma unroll
  for (int off = 1; off < 64; off <<= 1) l += __shfl_xor(l, off);
  __syncthreads();
  if (lane == 0) red[wave] = l;
  __syncthreads();
  const float li = 1.f / (red[0] + red[1] + red[2] + red[3]);

#pragma unroll
  for (int t = 0; t < 4; ++t) {
    ushort4 o;
    o.x = f2b(e[4 * t + 0] * li);
    o.y = f2b(e[4 * t + 1] * li);
    o.z = f2b(e[4 * t + 2] * li);
    o.w = f2b(e[4 * t + 3] * li);
    dst[tid + t * 256] = o;
  }
}

// ---------------- launcher ----------------
// ws (136 MB):
//  [0,8M) Xh  [8,16M) Xl  [16,22M) WtH[3072][1024]  [22,26M) WtL[2048][1024]
//  [0,32M)  P (overlays X/W after projections)
//  [32,36) Qa  [36,40) Qb  [40,44) Ka  [44,48) Kb   (int8 planes)
//  [64,72) Vt[1024][4096] bf16
//  [72,136) Ss fp32 [4096][4096]

extern "C" void kernel_launch(void* const* d_in, const int* in_sizes, int n_in,
                              void* d_out, int out_size, void* d_ws, size_t ws_size,
                              hipStream_t stream) {
  const float* X  = (const float*)d_in[0];
  const float* Wq = (const float*)d_in[1];
  const float* Wk = (const float*)d_in[2];
  const float* Wv = (const float*)d_in[3];
  float* O = (float*)d_out;
  char* ws = (char*)d_ws;

  const size_t MB = 1u << 20;
  u16*   Xh  = (u16*)(ws);
  u16*   Xl  = (u16*)(ws + 8 * MB);
  u16*   WtH = (u16*)(ws + 16 * MB);
  u16*   WtL = (u16*)(ws + 22 * MB);
  u16*   P   = (u16*)(ws);
  char*  Qa  = (char*)(ws + 32 * MB);
  char*  Qb  = (char*)(ws + 36 * MB);
  char*  Ka  = (char*)(ws + 40 * MB);
  char*  Kb  = (char*)(ws + 44 * MB);
  u16*   Vt  = (u16*)(ws + 64 * MB);
  float* Ss  = (float*)(ws + 72 * MB);

  // O accumulated by atomic split-K PV: zero it first
  hipMemsetAsync(O, 0, (size_t)S_SEQ * D_OUT * sizeof(float), stream);

  // phase A: conversions
  split_bf16_kernel<<<(S_SEQ * D_IN / 4 + 255) / 256, 256, 0, stream>>>(
      X, Xh, Xl, S_SEQ * D_IN / 4);
  transpose_w_kernel<<<dim3(32, 32, 3), dim3(32, 8), 0, stream>>>(
      Wq, Wk, Wv, WtH, WtL);

  // phase B: merged QKV projection (768 blocks)
  qkv_kernel<<<dim3(3072 / 128, S_SEQ / 128), 256, 0, stream>>>(
      Xh, Xl, WtH, WtL, Qa, Qb, Ka, Kb, Vt);

  // phase B2: S = QK^T/32 fp32, i8 MFMA (2048 blocks, 128x64 tile, BK=128)
  s_i8_kernel<<<dim3(S_SEQ / 64, S_SEQ / 128), 256, 0, stream>>>(
      Qa, Qb, Ka, Kb, Ss);

  // phase C: single-pass softmax
  softmax_kernel<<<S_SEQ, 256, 0, stream>>>(Ss, P);

  // phase D: O += P.V, split-K4, atomic, XCD-local grid (x=bm)
  pv_kernel<<<dim3(S_SEQ / 128, D_OUT / 128, 4), 256, 0, stream>>>(P, Vt, O);
}

// Round 9
// 280.494 us; speedup vs baseline: 1.1033x; 1.1033x over previous
//
#include <hip/hip_runtime.h>
#include <hip/hip_bf16.h>
#include <cstdint>
#include <type_traits>

// SingleHeadAttention. Numerics (validated r2-r8, absmax 1.0):
//   Q/K proj: 3-term split-bf16 MFMA; Q,K quantized int16-fixed (q=a*256+b);
//   S = (H<<16+M<<8+L)*2^-21 exact -> fp32 (i16-S clamps! r6); V/P/PV bf16.
// r9: PV epilogue de-atomicized. r8 showed the K-loop fixes worked (FETCH
//   135->49MB ideal, conflicts 4.2M->0) but split-K4 doubled atomics and PV
//   got slower (83->90.7, MfmaUtil 14%). Now: 4 non-atomic O-slices written
//   to the dead Ss region + add4 reduce pass. Clean attribution: if PV drops
//   to ~55-60 the atomics were the cost; if not, K-loop latency is structural.

using u16 = unsigned short;
typedef __attribute__((ext_vector_type(8))) short short8;
typedef __attribute__((ext_vector_type(4))) float floatx4;
typedef __attribute__((ext_vector_type(4))) int intx4;

static constexpr int S_SEQ = 4096;
static constexpr int D_IN  = 1024;
static constexpr int D_OUT = 1024;

__device__ __forceinline__ u16 f2b(float f) {
  uint32_t u = __builtin_bit_cast(uint32_t, f);
  u = (u + 0x7FFFu + ((u >> 16) & 1u)) >> 16;
  return (u16)u;
}
__device__ __forceinline__ float b2f(u16 b) {
  return __builtin_bit_cast(float, (uint32_t)b << 16);
}
__device__ __forceinline__ void load16(const void* g, void* l) {
  __builtin_amdgcn_global_load_lds(
      (const __attribute__((address_space(1))) void*)g,
      (__attribute__((address_space(3))) void*)l,
      16, 0, 0);
}

// ---------------- conversions ----------------

__global__ void split_bf16_kernel(const float* __restrict__ in,
                                  u16* __restrict__ hi, u16* __restrict__ lo,
                                  int n4) {
  int i = blockIdx.x * blockDim.x + threadIdx.x;
  if (i >= n4) return;
  float4 v = reinterpret_cast<const float4*>(in)[i];
  ushort4 h, l;
  h.x = f2b(v.x); l.x = f2b(v.x - b2f(h.x));
  h.y = f2b(v.y); l.y = f2b(v.y - b2f(h.y));
  h.z = f2b(v.z); l.z = f2b(v.z - b2f(h.z));
  h.w = f2b(v.w); l.w = f2b(v.w - b2f(h.w));
  reinterpret_cast<ushort4*>(hi)[i] = h;
  reinterpret_cast<ushort4*>(lo)[i] = l;
}

// z=0:Wq z=1:Wk (split H+L), z=2:Wv (H only). WtH[3072][1024], WtL[2048][1024]
__global__ void transpose_w_kernel(const float* __restrict__ Wq,
                                   const float* __restrict__ Wk,
                                   const float* __restrict__ Wv,
                                   u16* __restrict__ WtH, u16* __restrict__ WtL) {
  const int z = blockIdx.z;
  const float* src = (z == 0) ? Wq : (z == 1) ? Wk : Wv;
  u16* dH = WtH + (size_t)z * 1024 * 1024;
  u16* dL = (z < 2) ? WtL + (size_t)z * 1024 * 1024 : nullptr;
  __shared__ float tile[32][33];
  int bx = blockIdx.x * 32, by = blockIdx.y * 32;
  int tx = threadIdx.x, ty = threadIdx.y;   // block (32,8)
  for (int j = 0; j < 32; j += 8)
    tile[ty + j][tx] = src[(size_t)(by + ty + j) * 1024 + bx + tx];
  __syncthreads();
  for (int j = 0; j < 32; j += 8) {
    float v = tile[tx][ty + j];
    u16 h = f2b(v);
    size_t idx = (size_t)(bx + ty + j) * 1024 + by + tx;
    dH[idx] = h;
    if (dL) dL[idx] = f2b(v - b2f(h));
  }
}

// ---------------- merged QKV projection (split-bf16 compute) ----------------
__global__ __launch_bounds__(256)
void qkv_kernel(const u16* __restrict__ Xh, const u16* __restrict__ Xl,
                const u16* __restrict__ WtH, const u16* __restrict__ WtL,
                char* __restrict__ Qa, char* __restrict__ Qb,
                char* __restrict__ Ka, char* __restrict__ Kb,
                u16* __restrict__ Vt) {
  constexpr int BK = 32, K = D_IN;
  constexpr int TILE = 128 * BK;
  __shared__ __align__(16) u16 smem[4 * TILE];
  u16* AsH = smem;
  u16* BsH = smem + TILE;
  u16* AsL = smem + 2 * TILE;
  u16* BsL = smem + 3 * TILE;

  const int tid  = threadIdx.x;
  const int wave = tid >> 6;
  const int lane = tid & 63;
  const int bm   = blockIdx.y * 128;
  const int bn   = blockIdx.x * 128;     // [0,3072)
  const bool splitB = bn < 2048;
  const int wm   = (wave >> 1) * 64;
  const int wn   = (wave & 1) * 64;
  const int quad = lane >> 4;
  const int l16  = lane & 15;

  const int srow = wave * 16 + (lane >> 2);
  const int scol = (lane & 3) * 8;
  const size_t offA = (size_t)(bm + srow) * K + scol;
  const size_t offB = (size_t)(bn + srow) * K + scol;
  const size_t off64 = (size_t)64 * K;
  const int lds0 = wave * 512;
  const int lds1 = 2048 + wave * 512;

  floatx4 acc[4][4] = {};

  for (int k0 = 0; k0 < K; k0 += BK) {
    __syncthreads();
    load16(Xh + offA + k0,          AsH + lds0);
    load16(Xh + offA + off64 + k0,  AsH + lds1);
    load16(WtH + offB + k0,         BsH + lds0);
    load16(WtH + offB + off64 + k0, BsH + lds1);
    if (splitB) {
      load16(Xl + offA + k0,          AsL + lds0);
      load16(Xl + offA + off64 + k0,  AsL + lds1);
      load16(WtL + offB + k0,         BsL + lds0);
      load16(WtL + offB + off64 + k0, BsL + lds1);
    }
    __syncthreads();

    short8 ah[4], bh[4], al[4], bl[4];
#pragma unroll
    for (int t = 0; t < 4; ++t) {
      ah[t] = *reinterpret_cast<const short8*>(AsH + (wm + t * 16 + l16) * BK + quad * 8);
      bh[t] = *reinterpret_cast<const short8*>(BsH + (wn + t * 16 + l16) * BK + quad * 8);
    }
    if (splitB) {
#pragma unroll
      for (int t = 0; t < 4; ++t) {
        al[t] = *reinterpret_cast<const short8*>(AsL + (wm + t * 16 + l16) * BK + quad * 8);
        bl[t] = *reinterpret_cast<const short8*>(BsL + (wn + t * 16 + l16) * BK + quad * 8);
      }
    }

#pragma unroll
    for (int mt = 0; mt < 4; ++mt)
#pragma unroll
      for (int nt = 0; nt < 4; ++nt)
        acc[mt][nt] = __builtin_amdgcn_mfma_f32_16x16x32_bf16(
            ah[mt], bh[nt], acc[mt][nt], 0, 0, 0);
    if (splitB) {
#pragma unroll
      for (int mt = 0; mt < 4; ++mt)
#pragma unroll
        for (int nt = 0; nt < 4; ++nt) {
          acc[mt][nt] = __builtin_amdgcn_mfma_f32_16x16x32_bf16(
              ah[mt], bl[nt], acc[mt][nt], 0, 0, 0);
          acc[mt][nt] = __builtin_amdgcn_mfma_f32_16x16x32_bf16(
              al[mt], bh[nt], acc[mt][nt], 0, 0, 0);
        }
    }
  }

  // epilogue (C/D: col=lane&15, row=quad*4+reg)
#pragma unroll
  for (int mt = 0; mt < 4; ++mt) {
#pragma unroll
    for (int nt = 0; nt < 4; ++nt) {
      const int row = bm + wm + mt * 16 + quad * 4;
      const int col = bn + wn + nt * 16 + l16;
      if (bn < 2048) {                 // Q or K -> int16-fixed byte planes
        char* Pa = (bn < 1024) ? Qa : Ka;
        char* Pb = (bn < 1024) ? Qb : Kb;
        const int c = (bn < 1024) ? col : col - 1024;
#pragma unroll
        for (int r = 0; r < 4; ++r) {
          float v = acc[mt][nt][r];
          int q16 = (int)rintf(v * 256.f);
          q16 = min(max(q16, -32512), 32512);    // |Q| <= 127 (6.9 sigma)
          int a = (q16 + 128) >> 8;              // a in [-127,127]
          int b = q16 - (a << 8);                // b in [-128,127]
          size_t idx = (size_t)(row + r) * 1024 + c;
          Pa[idx] = (char)a;
          Pb[idx] = (char)b;
        }
      } else {                         // V, write transposed, packed 8B store
        ushort4 o;
        o.x = f2b(acc[mt][nt][0]);
        o.y = f2b(acc[mt][nt][1]);
        o.z = f2b(acc[mt][nt][2]);
        o.w = f2b(acc[mt][nt][3]);
        *reinterpret_cast<ushort4*>(Vt + (size_t)(col - 2048) * S_SEQ + row) = o;
      }
    }
  }
}

// ---------------- i8 fixed-point S GEMM ----------------
// S[m][n] = (H<<16 + M<<8 + L) * 2^-21  (fp32; exact int recombine)
// Tile 128x64, BK=128 bytes, 8 iters. LDS rows 128B = 8 chunks of 16B;
// chunk g of row R stored at slot g^(R&7) -> conflict-free b128 frag reads.
__global__ __launch_bounds__(256)
void s_i8_kernel(const char* __restrict__ Qa, const char* __restrict__ Qb,
                 const char* __restrict__ Ka, const char* __restrict__ Kb,
                 float* __restrict__ S) {
  constexpr int K = D_IN, BK = 128;
  __shared__ __align__(16) char smem[48 * 1024];
  char* QaS = smem;                // [128][128]
  char* QbS = smem + 16384;        // [128][128]
  char* KaS = smem + 32768;        // [64][128]
  char* KbS = smem + 40960;        // [64][128]

  const int tid  = threadIdx.x;
  const int wave = tid >> 6;
  const int lane = tid & 63;
  const int bm   = blockIdx.y * 128;
  const int bn   = blockIdx.x * 64;
  const int wm   = (wave >> 1) * 64;
  const int wn   = (wave & 1) * 32;
  const int quad = lane >> 4;
  const int l16  = lane & 15;

  // staging: 8 rows x 128B per wave-issue; lane -> (row=srow, chunk=(lane&7)^srow)
  const int srow = lane >> 3;                 // 0..7
  const int scol = ((lane & 7) ^ srow) * 16;  // XOR swizzle
  int gQ[4], gK[2];
#pragma unroll
  for (int j = 0; j < 4; ++j)
    gQ[j] = (bm + j * 32 + wave * 8 + srow) * K + scol;
#pragma unroll
  for (int j = 0; j < 2; ++j)
    gK[j] = (bn + j * 32 + wave * 8 + srow) * K + scol;
  const int lQ[4] = {(0 * 32 + wave * 8) * 128, (1 * 32 + wave * 8) * 128,
                     (2 * 32 + wave * 8) * 128, (3 * 32 + wave * 8) * 128};
  const int lK[2] = {(0 * 32 + wave * 8) * 128, (1 * 32 + wave * 8) * 128};

  // frag reads: row R, global chunk g=quad+4s at slot (g^(R&7))
  const int r7 = l16 & 7;
  int cA[4], cB[2];
#pragma unroll
  for (int t = 0; t < 4; ++t)
    cA[t] = (wm + t * 16 + l16) * 128 + ((quad ^ r7) * 16);
#pragma unroll
  for (int t = 0; t < 2; ++t)
    cB[t] = (wn + t * 16 + l16) * 128 + ((quad ^ r7) * 16);

  intx4 accH[4][2] = {};
  intx4 accM[4][2] = {};
  intx4 accL[4][2] = {};

  for (int k0 = 0; k0 < K; k0 += BK) {
    __syncthreads();
#pragma unroll
    for (int j = 0; j < 4; ++j) {
      load16(Qa + gQ[j] + k0, QaS + lQ[j]);
      load16(Qb + gQ[j] + k0, QbS + lQ[j]);
    }
#pragma unroll
    for (int j = 0; j < 2; ++j) {
      load16(Ka + gK[j] + k0, KaS + lK[j]);
      load16(Kb + gK[j] + k0, KbS + lK[j]);
    }
    __syncthreads();

#pragma unroll
    for (int s = 0; s < 2; ++s) {
      const int so = s * 64;
      intx4 ah[4], al[4];
#pragma unroll
      for (int t = 0; t < 4; ++t) {
        ah[t] = *reinterpret_cast<const intx4*>(QaS + (cA[t] ^ so));
        al[t] = *reinterpret_cast<const intx4*>(QbS + (cA[t] ^ so));
      }
#pragma unroll
      for (int nt = 0; nt < 2; ++nt) {
        intx4 bh = *reinterpret_cast<const intx4*>(KaS + (cB[nt] ^ so));
#pragma unroll
        for (int mt = 0; mt < 4; ++mt) {
          accH[mt][nt] = __builtin_amdgcn_mfma_i32_16x16x64_i8(ah[mt], bh, accH[mt][nt], 0, 0, 0);
          accM[mt][nt] = __builtin_amdgcn_mfma_i32_16x16x64_i8(al[mt], bh, accM[mt][nt], 0, 0, 0);
        }
        intx4 bl = *reinterpret_cast<const intx4*>(KbS + (cB[nt] ^ so));
#pragma unroll
        for (int mt = 0; mt < 4; ++mt) {
          accM[mt][nt] = __builtin_amdgcn_mfma_i32_16x16x64_i8(ah[mt], bl, accM[mt][nt], 0, 0, 0);
          accL[mt][nt] = __builtin_amdgcn_mfma_i32_16x16x64_i8(al[mt], bl, accL[mt][nt], 0, 0, 0);
        }
      }
    }
  }

  // epilogue: exact int64 recombine -> fp32, scale 2^-16 (fixed^2) * 2^-5 (1/32)
  constexpr float SC = 4.76837158203125e-07f;
#pragma unroll
  for (int mt = 0; mt < 4; ++mt)
#pragma unroll
    for (int nt = 0; nt < 2; ++nt) {
      const int row = bm + wm + mt * 16 + quad * 4;
      const int col = bn + wn + nt * 16 + l16;
#pragma unroll
      for (int r = 0; r < 4; ++r) {
        long long fix = (((long long)accH[mt][nt][r]) << 16) +
                        (((long long)accM[mt][nt][r]) << 8) +
                        (long long)accL[mt][nt][r];
        S[(size_t)(row + r) * S_SEQ + col] = (float)fix * SC;
      }
    }
}

// ---------------- PV GEMM: Osl[z] = P(bf16).V over K-slice z --------------
// Tile 128x128, BK=64 elems (128B LDS rows, chunk g of row R at slot g^(R&7)).
// Grid (x=bm 32, y=bn 8, z=4): XCD = id%8 = bm%8 -> P tiles L2-local per XCD.
// Non-atomic: each z writes its own 16MB slice (overlaid on dead Ss region).
__global__ __launch_bounds__(256)
void pv_kernel(const u16* __restrict__ P, const u16* __restrict__ Vt,
               float* __restrict__ Osl) {
  constexpr int LDA = S_SEQ;          // row stride of P and Vt (elements)
  constexpr int KS  = S_SEQ / 4;      // 1024 per z-slice
  constexpr int BK  = 64;
  __shared__ __align__(16) u16 smem[2 * 128 * 64];   // 32 KB
  u16* As = smem;                     // P tile   [128][64] swizzled
  u16* Bs = smem + 128 * 64;          // Vt tile  [128][64] swizzled

  const int tid  = threadIdx.x;
  const int wave = tid >> 6;
  const int lane = tid & 63;
  const int bm   = blockIdx.x * 128;
  const int bn   = blockIdx.y * 128;
  const int kz   = blockIdx.z * KS;
  const int wm   = (wave >> 1) * 64;
  const int wn   = (wave & 1) * 64;
  const int quad = lane >> 4;
  const int l16  = lane & 15;

  // staging: 8 rows x 128B per issue; lane -> (row=srow, chunk=(lane&7)^srow)
  const int srow  = lane >> 3;
  const int selem = ((lane & 7) ^ srow) * 8;     // element offset within row
  size_t gA[4], gB[4];
#pragma unroll
  for (int j = 0; j < 4; ++j) {
    gA[j] = (size_t)(bm + j * 32 + wave * 8 + srow) * LDA + kz + selem;
    gB[j] = (size_t)(bn + j * 32 + wave * 8 + srow) * LDA + kz + selem;
  }
  const int lds[4] = {(wave * 8 + 0) * 64, (wave * 8 + 32) * 64,
                      (wave * 8 + 64) * 64, (wave * 8 + 96) * 64};

  // frag reads: row R, k-chunk g=quad+4s (8 elems) at slot g^(R&7)
  int cA[4], cB[4];
#pragma unroll
  for (int t = 0; t < 4; ++t) {
    const int Ra = wm + t * 16 + l16;
    const int Rb = wn + t * 16 + l16;
    cA[t] = Ra * 64 + ((quad ^ (Ra & 7)) * 8);
    cB[t] = Rb * 64 + ((quad ^ (Rb & 7)) * 8);
  }

  floatx4 acc[4][4] = {};

  for (int k0 = 0; k0 < KS; k0 += BK) {
    __syncthreads();
#pragma unroll
    for (int j = 0; j < 4; ++j) {
      load16(P + gA[j] + k0,  As + lds[j]);
      load16(Vt + gB[j] + k0, Bs + lds[j]);
    }
    __syncthreads();

#pragma unroll
    for (int s = 0; s < 2; ++s) {
      const int so = s * 32;              // flips slot bit 2 (u16 units)
      short8 af[4], bf[4];
#pragma unroll
      for (int t = 0; t < 4; ++t) {
        af[t] = *reinterpret_cast<const short8*>(As + (cA[t] ^ so));
        bf[t] = *reinterpret_cast<const short8*>(Bs + (cB[t] ^ so));
      }
#pragma unroll
      for (int mt = 0; mt < 4; ++mt)
#pragma unroll
        for (int nt = 0; nt < 4; ++nt)
          acc[mt][nt] = __builtin_amdgcn_mfma_f32_16x16x32_bf16(
              af[mt], bf[nt], acc[mt][nt], 0, 0, 0);
    }
  }

  float* C = Osl + (size_t)blockIdx.z * S_SEQ * D_OUT;
#pragma unroll
  for (int mt = 0; mt < 4; ++mt)
#pragma unroll
    for (int nt = 0; nt < 4; ++nt) {
      const int row = bm + wm + mt * 16 + quad * 4;
      const int col = bn + wn + nt * 16 + l16;
#pragma unroll
      for (int r = 0; r < 4; ++r)
        C[(size_t)(row + r) * D_OUT + col] = acc[mt][nt][r];
    }
}

// ---------------- split-K reduce: O = s0+s1+s2+s3 ----------------
__global__ void add4_kernel(const float* __restrict__ s,
                            float* __restrict__ o, int n4) {
  int i = blockIdx.x * blockDim.x + threadIdx.x;
  if (i >= n4) return;
  const float4* s4 = reinterpret_cast<const float4*>(s);
  float4 x = s4[i];
  float4 y = s4[i + n4];
  float4 z = s4[i + 2 * n4];
  float4 w = s4[i + 3 * n4];
  x.x += y.x + z.x + w.x;
  x.y += y.y + z.y + w.y;
  x.z += y.z + z.z + w.z;
  x.w += y.w + z.w + w.w;
  reinterpret_cast<float4*>(o)[i] = x;
}

// ---------------- single-pass softmax (block per row, fp32 input) ----------
__global__ __launch_bounds__(256)
void softmax_kernel(const float* __restrict__ S, u16* __restrict__ P) {
  const int row = blockIdx.x, tid = threadIdx.x;
  const int lane = tid & 63, wave = tid >> 6;
  __shared__ float red[4];
  const float4* src = reinterpret_cast<const float4*>(S + (size_t)row * S_SEQ);
  ushort4* dst = reinterpret_cast<ushort4*>(P + (size_t)row * S_SEQ);

  float4 v[4];
  float m = -INFINITY;
#pragma unroll
  for (int t = 0; t < 4; ++t) {
    v[t] = src[tid + t * 256];
    m = fmaxf(m, fmaxf(fmaxf(v[t].x, v[t].y), fmaxf(v[t].z, v[t].w)));
  }
#pragma unroll
  for (int off = 1; off < 64; off <<= 1) m = fmaxf(m, __shfl_xor(m, off));
  if (lane == 0) red[wave] = m;
  __syncthreads();
  m = fmaxf(fmaxf(red[0], red[1]), fmaxf(red[2], red[3]));

  float e[16];
  float l = 0.f;
#pragma unroll
  for (int t = 0; t < 4; ++t) {
    e[4 * t + 0] = __expf(v[t].x - m);
    e[4 * t + 1] = __expf(v[t].y - m);
    e[4 * t + 2] = __expf(v[t].z - m);
    e[4 * t + 3] = __expf(v[t].w - m);
    l += e[4 * t + 0] + e[4 * t + 1] + e[4 * t + 2] + e[4 * t + 3];
  }
#pragma unroll
  for (int off = 1; off < 64; off <<= 1) l += __shfl_xor(l, off);
  __syncthreads();
  if (lane == 0) red[wave] = l;
  __syncthreads();
  const float li = 1.f / (red[0] + red[1] + red[2] + red[3]);

#pragma unroll
  for (int t = 0; t < 4; ++t) {
    ushort4 o;
    o.x = f2b(e[4 * t + 0] * li);
    o.y = f2b(e[4 * t + 1] * li);
    o.z = f2b(e[4 * t + 2] * li);
    o.w = f2b(e[4 * t + 3] * li);
    dst[tid + t * 256] = o;
  }
}

// ---------------- launcher ----------------
// ws (136 MB):
//  [0,8M) Xh  [8,16M) Xl  [16,22M) WtH[3072][1024]  [22,26M) WtL[2048][1024]
//  [0,32M)  P (overlays X/W after projections)
//  [32,36) Qa  [36,40) Qb  [40,44) Ka  [44,48) Kb   (int8 planes)
//  [64,72) Vt[1024][4096] bf16
//  [72,136) Ss fp32 [4096][4096]; PV O-slices 4x16MB overlay Ss (dead post-softmax)

extern "C" void kernel_launch(void* const* d_in, const int* in_sizes, int n_in,
                              void* d_out, int out_size, void* d_ws, size_t ws_size,
                              hipStream_t stream) {
  const float* X  = (const float*)d_in[0];
  const float* Wq = (const float*)d_in[1];
  const float* Wk = (const float*)d_in[2];
  const float* Wv = (const float*)d_in[3];
  float* O = (float*)d_out;
  char* ws = (char*)d_ws;

  const size_t MB = 1u << 20;
  u16*   Xh  = (u16*)(ws);
  u16*   Xl  = (u16*)(ws + 8 * MB);
  u16*   WtH = (u16*)(ws + 16 * MB);
  u16*   WtL = (u16*)(ws + 22 * MB);
  u16*   P   = (u16*)(ws);
  char*  Qa  = (char*)(ws + 32 * MB);
  char*  Qb  = (char*)(ws + 36 * MB);
  char*  Ka  = (char*)(ws + 40 * MB);
  char*  Kb  = (char*)(ws + 44 * MB);
  u16*   Vt  = (u16*)(ws + 64 * MB);
  float* Ss  = (float*)(ws + 72 * MB);
  float* Osl = (float*)(ws + 72 * MB);   // 4 x 16MB slices, overlays dead Ss

  // phase A: conversions
  split_bf16_kernel<<<(S_SEQ * D_IN / 4 + 255) / 256, 256, 0, stream>>>(
      X, Xh, Xl, S_SEQ * D_IN / 4);
  transpose_w_kernel<<<dim3(32, 32, 3), dim3(32, 8), 0, stream>>>(
      Wq, Wk, Wv, WtH, WtL);

  // phase B: merged QKV projection (768 blocks)
  qkv_kernel<<<dim3(3072 / 128, S_SEQ / 128), 256, 0, stream>>>(
      Xh, Xl, WtH, WtL, Qa, Qb, Ka, Kb, Vt);

  // phase B2: S = QK^T/32 fp32, i8 MFMA (2048 blocks, 128x64 tile, BK=128)
  s_i8_kernel<<<dim3(S_SEQ / 64, S_SEQ / 128), 256, 0, stream>>>(
      Qa, Qb, Ka, Kb, Ss);

  // phase C: single-pass softmax
  softmax_kernel<<<S_SEQ, 256, 0, stream>>>(Ss, P);

  // phase D: O-slices = P.V per K-quarter (1024 blocks, non-atomic), then add4
  pv_kernel<<<dim3(S_SEQ / 128, D_OUT / 128, 4), 256, 0, stream>>>(P, Vt, Osl);
  add4_kernel<<<(S_SEQ * D_OUT / 4 + 255) / 256, 256, 0, stream>>>(
      Osl, O, S_SEQ * D_OUT / 4);
}

// Round 10
// 277.704 us; speedup vs baseline: 1.1144x; 1.0100x over previous
//
#include <hip/hip_runtime.h>
#include <hip/hip_bf16.h>
#include <cstdint>
#include <type_traits>

// SingleHeadAttention. Numerics (validated r2-r9, absmax 1.0):
//   Q/K proj: 3-term split-bf16 MFMA; Q,K quantized int16-fixed (q=a*256+b);
//   S = (H<<16+M<<8+L)*2^-21 exact -> fp32 (i16-S clamps! r6); V/P/PV bf16.
// r10: PV latency attack (r9 showed PV ~6x over floor, P loads at HBM latency):
//   - grid (x=bn 8, y=bm 32, z=4): XCD = id%8 = bn -> Vt slice 1MB L2-resident
//     per XCD; P streams via shared L3 (~350cyc) instead of HBM (~900cyc).
//   - BK=128 elems (256B LDS rows, 16-chunk XOR swizzle by R&7): 64 MFMA per
//     iter per wave, 16 iters = half the barrier drains. LDS 64KB.

using u16 = unsigned short;
typedef __attribute__((ext_vector_type(8))) short short8;
typedef __attribute__((ext_vector_type(4))) float floatx4;
typedef __attribute__((ext_vector_type(4))) int intx4;

static constexpr int S_SEQ = 4096;
static constexpr int D_IN  = 1024;
static constexpr int D_OUT = 1024;

__device__ __forceinline__ u16 f2b(float f) {
  uint32_t u = __builtin_bit_cast(uint32_t, f);
  u = (u + 0x7FFFu + ((u >> 16) & 1u)) >> 16;
  return (u16)u;
}
__device__ __forceinline__ float b2f(u16 b) {
  return __builtin_bit_cast(float, (uint32_t)b << 16);
}
__device__ __forceinline__ void load16(const void* g, void* l) {
  __builtin_amdgcn_global_load_lds(
      (const __attribute__((address_space(1))) void*)g,
      (__attribute__((address_space(3))) void*)l,
      16, 0, 0);
}

// ---------------- conversions ----------------

__global__ void split_bf16_kernel(const float* __restrict__ in,
                                  u16* __restrict__ hi, u16* __restrict__ lo,
                                  int n4) {
  int i = blockIdx.x * blockDim.x + threadIdx.x;
  if (i >= n4) return;
  float4 v = reinterpret_cast<const float4*>(in)[i];
  ushort4 h, l;
  h.x = f2b(v.x); l.x = f2b(v.x - b2f(h.x));
  h.y = f2b(v.y); l.y = f2b(v.y - b2f(h.y));
  h.z = f2b(v.z); l.z = f2b(v.z - b2f(h.z));
  h.w = f2b(v.w); l.w = f2b(v.w - b2f(h.w));
  reinterpret_cast<ushort4*>(hi)[i] = h;
  reinterpret_cast<ushort4*>(lo)[i] = l;
}

// z=0:Wq z=1:Wk (split H+L), z=2:Wv (H only). WtH[3072][1024], WtL[2048][1024]
__global__ void transpose_w_kernel(const float* __restrict__ Wq,
                                   const float* __restrict__ Wk,
                                   const float* __restrict__ Wv,
                                   u16* __restrict__ WtH, u16* __restrict__ WtL) {
  const int z = blockIdx.z;
  const float* src = (z == 0) ? Wq : (z == 1) ? Wk : Wv;
  u16* dH = WtH + (size_t)z * 1024 * 1024;
  u16* dL = (z < 2) ? WtL + (size_t)z * 1024 * 1024 : nullptr;
  __shared__ float tile[32][33];
  int bx = blockIdx.x * 32, by = blockIdx.y * 32;
  int tx = threadIdx.x, ty = threadIdx.y;   // block (32,8)
  for (int j = 0; j < 32; j += 8)
    tile[ty + j][tx] = src[(size_t)(by + ty + j) * 1024 + bx + tx];
  __syncthreads();
  for (int j = 0; j < 32; j += 8) {
    float v = tile[tx][ty + j];
    u16 h = f2b(v);
    size_t idx = (size_t)(bx + ty + j) * 1024 + by + tx;
    dH[idx] = h;
    if (dL) dL[idx] = f2b(v - b2f(h));
  }
}

// ---------------- merged QKV projection (split-bf16 compute) ----------------
__global__ __launch_bounds__(256)
void qkv_kernel(const u16* __restrict__ Xh, const u16* __restrict__ Xl,
                const u16* __restrict__ WtH, const u16* __restrict__ WtL,
                char* __restrict__ Qa, char* __restrict__ Qb,
                char* __restrict__ Ka, char* __restrict__ Kb,
                u16* __restrict__ Vt) {
  constexpr int BK = 32, K = D_IN;
  constexpr int TILE = 128 * BK;
  __shared__ __align__(16) u16 smem[4 * TILE];
  u16* AsH = smem;
  u16* BsH = smem + TILE;
  u16* AsL = smem + 2 * TILE;
  u16* BsL = smem + 3 * TILE;

  const int tid  = threadIdx.x;
  const int wave = tid >> 6;
  const int lane = tid & 63;
  const int bm   = blockIdx.y * 128;
  const int bn   = blockIdx.x * 128;     // [0,3072)
  const bool splitB = bn < 2048;
  const int wm   = (wave >> 1) * 64;
  const int wn   = (wave & 1) * 64;
  const int quad = lane >> 4;
  const int l16  = lane & 15;

  const int srow = wave * 16 + (lane >> 2);
  const int scol = (lane & 3) * 8;
  const size_t offA = (size_t)(bm + srow) * K + scol;
  const size_t offB = (size_t)(bn + srow) * K + scol;
  const size_t off64 = (size_t)64 * K;
  const int lds0 = wave * 512;
  const int lds1 = 2048 + wave * 512;

  floatx4 acc[4][4] = {};

  for (int k0 = 0; k0 < K; k0 += BK) {
    __syncthreads();
    load16(Xh + offA + k0,          AsH + lds0);
    load16(Xh + offA + off64 + k0,  AsH + lds1);
    load16(WtH + offB + k0,         BsH + lds0);
    load16(WtH + offB + off64 + k0, BsH + lds1);
    if (splitB) {
      load16(Xl + offA + k0,          AsL + lds0);
      load16(Xl + offA + off64 + k0,  AsL + lds1);
      load16(WtL + offB + k0,         BsL + lds0);
      load16(WtL + offB + off64 + k0, BsL + lds1);
    }
    __syncthreads();

    short8 ah[4], bh[4], al[4], bl[4];
#pragma unroll
    for (int t = 0; t < 4; ++t) {
      ah[t] = *reinterpret_cast<const short8*>(AsH + (wm + t * 16 + l16) * BK + quad * 8);
      bh[t] = *reinterpret_cast<const short8*>(BsH + (wn + t * 16 + l16) * BK + quad * 8);
    }
    if (splitB) {
#pragma unroll
      for (int t = 0; t < 4; ++t) {
        al[t] = *reinterpret_cast<const short8*>(AsL + (wm + t * 16 + l16) * BK + quad * 8);
        bl[t] = *reinterpret_cast<const short8*>(BsL + (wn + t * 16 + l16) * BK + quad * 8);
      }
    }

#pragma unroll
    for (int mt = 0; mt < 4; ++mt)
#pragma unroll
      for (int nt = 0; nt < 4; ++nt)
        acc[mt][nt] = __builtin_amdgcn_mfma_f32_16x16x32_bf16(
            ah[mt], bh[nt], acc[mt][nt], 0, 0, 0);
    if (splitB) {
#pragma unroll
      for (int mt = 0; mt < 4; ++mt)
#pragma unroll
        for (int nt = 0; nt < 4; ++nt) {
          acc[mt][nt] = __builtin_amdgcn_mfma_f32_16x16x32_bf16(
              ah[mt], bl[nt], acc[mt][nt], 0, 0, 0);
          acc[mt][nt] = __builtin_amdgcn_mfma_f32_16x16x32_bf16(
              al[mt], bh[nt], acc[mt][nt], 0, 0, 0);
        }
    }
  }

  // epilogue (C/D: col=lane&15, row=quad*4+reg)
#pragma unroll
  for (int mt = 0; mt < 4; ++mt) {
#pragma unroll
    for (int nt = 0; nt < 4; ++nt) {
      const int row = bm + wm + mt * 16 + quad * 4;
      const int col = bn + wn + nt * 16 + l16;
      if (bn < 2048) {                 // Q or K -> int16-fixed byte planes
        char* Pa = (bn < 1024) ? Qa : Ka;
        char* Pb = (bn < 1024) ? Qb : Kb;
        const int c = (bn < 1024) ? col : col - 1024;
#pragma unroll
        for (int r = 0; r < 4; ++r) {
          float v = acc[mt][nt][r];
          int q16 = (int)rintf(v * 256.f);
          q16 = min(max(q16, -32512), 32512);    // |Q| <= 127 (6.9 sigma)
          int a = (q16 + 128) >> 8;              // a in [-127,127]
          int b = q16 - (a << 8);                // b in [-128,127]
          size_t idx = (size_t)(row + r) * 1024 + c;
          Pa[idx] = (char)a;
          Pb[idx] = (char)b;
        }
      } else {                         // V, write transposed, packed 8B store
        ushort4 o;
        o.x = f2b(acc[mt][nt][0]);
        o.y = f2b(acc[mt][nt][1]);
        o.z = f2b(acc[mt][nt][2]);
        o.w = f2b(acc[mt][nt][3]);
        *reinterpret_cast<ushort4*>(Vt + (size_t)(col - 2048) * S_SEQ + row) = o;
      }
    }
  }
}

// ---------------- i8 fixed-point S GEMM ----------------
// S[m][n] = (H<<16 + M<<8 + L) * 2^-21  (fp32; exact int recombine)
// Tile 128x64, BK=128 bytes, 8 iters. LDS rows 128B = 8 chunks of 16B;
// chunk g of row R stored at slot g^(R&7) -> balanced b128 frag reads.
__global__ __launch_bounds__(256)
void s_i8_kernel(const char* __restrict__ Qa, const char* __restrict__ Qb,
                 const char* __restrict__ Ka, const char* __restrict__ Kb,
                 float* __restrict__ S) {
  constexpr int K = D_IN, BK = 128;
  __shared__ __align__(16) char smem[48 * 1024];
  char* QaS = smem;                // [128][128]
  char* QbS = smem + 16384;        // [128][128]
  char* KaS = smem + 32768;        // [64][128]
  char* KbS = smem + 40960;        // [64][128]

  const int tid  = threadIdx.x;
  const int wave = tid >> 6;
  const int lane = tid & 63;
  const int bm   = blockIdx.y * 128;
  const int bn   = blockIdx.x * 64;
  const int wm   = (wave >> 1) * 64;
  const int wn   = (wave & 1) * 32;
  const int quad = lane >> 4;
  const int l16  = lane & 15;

  // staging: 8 rows x 128B per wave-issue; lane -> (row=srow, chunk=(lane&7)^srow)
  const int srow = lane >> 3;                 // 0..7
  const int scol = ((lane & 7) ^ srow) * 16;  // XOR swizzle
  int gQ[4], gK[2];
#pragma unroll
  for (int j = 0; j < 4; ++j)
    gQ[j] = (bm + j * 32 + wave * 8 + srow) * K + scol;
#pragma unroll
  for (int j = 0; j < 2; ++j)
    gK[j] = (bn + j * 32 + wave * 8 + srow) * K + scol;
  const int lQ[4] = {(0 * 32 + wave * 8) * 128, (1 * 32 + wave * 8) * 128,
                     (2 * 32 + wave * 8) * 128, (3 * 32 + wave * 8) * 128};
  const int lK[2] = {(0 * 32 + wave * 8) * 128, (1 * 32 + wave * 8) * 128};

  // frag reads: row R, global chunk g=quad+4s at slot (g^(R&7))
  const int r7 = l16 & 7;
  int cA[4], cB[2];
#pragma unroll
  for (int t = 0; t < 4; ++t)
    cA[t] = (wm + t * 16 + l16) * 128 + ((quad ^ r7) * 16);
#pragma unroll
  for (int t = 0; t < 2; ++t)
    cB[t] = (wn + t * 16 + l16) * 128 + ((quad ^ r7) * 16);

  intx4 accH[4][2] = {};
  intx4 accM[4][2] = {};
  intx4 accL[4][2] = {};

  for (int k0 = 0; k0 < K; k0 += BK) {
    __syncthreads();
#pragma unroll
    for (int j = 0; j < 4; ++j) {
      load16(Qa + gQ[j] + k0, QaS + lQ[j]);
      load16(Qb + gQ[j] + k0, QbS + lQ[j]);
    }
#pragma unroll
    for (int j = 0; j < 2; ++j) {
      load16(Ka + gK[j] + k0, KaS + lK[j]);
      load16(Kb + gK[j] + k0, KbS + lK[j]);
    }
    __syncthreads();

#pragma unroll
    for (int s = 0; s < 2; ++s) {
      const int so = s * 64;
      intx4 ah[4], al[4];
#pragma unroll
      for (int t = 0; t < 4; ++t) {
        ah[t] = *reinterpret_cast<const intx4*>(QaS + (cA[t] ^ so));
        al[t] = *reinterpret_cast<const intx4*>(QbS + (cA[t] ^ so));
      }
#pragma unroll
      for (int nt = 0; nt < 2; ++nt) {
        intx4 bh = *reinterpret_cast<const intx4*>(KaS + (cB[nt] ^ so));
#pragma unroll
        for (int mt = 0; mt < 4; ++mt) {
          accH[mt][nt] = __builtin_amdgcn_mfma_i32_16x16x64_i8(ah[mt], bh, accH[mt][nt], 0, 0, 0);
          accM[mt][nt] = __builtin_amdgcn_mfma_i32_16x16x64_i8(al[mt], bh, accM[mt][nt], 0, 0, 0);
        }
        intx4 bl = *reinterpret_cast<const intx4*>(KbS + (cB[nt] ^ so));
#pragma unroll
        for (int mt = 0; mt < 4; ++mt) {
          accM[mt][nt] = __builtin_amdgcn_mfma_i32_16x16x64_i8(ah[mt], bl, accM[mt][nt], 0, 0, 0);
          accL[mt][nt] = __builtin_amdgcn_mfma_i32_16x16x64_i8(al[mt], bl, accL[mt][nt], 0, 0, 0);
        }
      }
    }
  }

  // epilogue: exact int64 recombine -> fp32, scale 2^-16 (fixed^2) * 2^-5 (1/32)
  constexpr float SC = 4.76837158203125e-07f;
#pragma unroll
  for (int mt = 0; mt < 4; ++mt)
#pragma unroll
    for (int nt = 0; nt < 2; ++nt) {
      const int row = bm + wm + mt * 16 + quad * 4;
      const int col = bn + wn + nt * 16 + l16;
#pragma unroll
      for (int r = 0; r < 4; ++r) {
        long long fix = (((long long)accH[mt][nt][r]) << 16) +
                        (((long long)accM[mt][nt][r]) << 8) +
                        (long long)accL[mt][nt][r];
        S[(size_t)(row + r) * S_SEQ + col] = (float)fix * SC;
      }
    }
}

// ---------------- PV GEMM: Osl[z] = P(bf16).V over K-slice z --------------
// Tile 128x128, BK=128 elems (256B LDS rows = 16 chunks of 16B; chunk g of
// row R at slot g^(R&7), bit 3 untouched -> balanced b128 reads).
// Grid (x=bn 8, y=bm 32, z=4): XCD = id%8 = bn -> this XCD's Vt slice (1MB)
// is L2-resident; P streams via the shared L3. Non-atomic slice writes.
__global__ __launch_bounds__(256)
void pv_kernel(const u16* __restrict__ P, const u16* __restrict__ Vt,
               float* __restrict__ Osl) {
  constexpr int LDA = S_SEQ;          // row stride of P and Vt (elements)
  constexpr int KS  = S_SEQ / 4;      // 1024 per z-slice
  constexpr int BK  = 128;
  __shared__ __align__(16) u16 smem[2 * 128 * 128];   // 64 KB
  u16* As = smem;                     // P tile   [128][128] swizzled
  u16* Bs = smem + 128 * 128;         // Vt tile  [128][128] swizzled

  const int tid  = threadIdx.x;
  const int wave = tid >> 6;
  const int lane = tid & 63;
  const int bn   = blockIdx.x * 128;  // XCD-local (gridDim.x = 8)
  const int bm   = blockIdx.y * 128;
  const int kz   = blockIdx.z * KS;
  const int wm   = (wave >> 1) * 64;
  const int wn   = (wave & 1) * 64;
  const int quad = lane >> 4;
  const int l16  = lane & 15;

  // staging: each issue = 4 rows x 256B; lane -> (srow=lane>>4, pos=lane&15).
  // LDS slot pos of row R holds global chunk pos^(R&7); R&7 = 4*(wave&1)+srow.
  const int srow = lane >> 4;                       // 0..3
  const int r7s  = 4 * (wave & 1) + srow;
  const int gcol = ((lane & 15) ^ r7s) * 8;         // element offset in row
  int gA[8], gB[8], lb[8];
#pragma unroll
  for (int j = 0; j < 8; ++j) {
    const int row = j * 16 + wave * 4;              // rows row..row+3 (srow)
    gA[j] = (bm + row + srow) * LDA + kz + gcol;
    gB[j] = (bn + row + srow) * LDA + kz + gcol;
    lb[j] = row * 128;                              // u16 offset, +lane*8 by HW
  }

  // frag reads: row R, k-step s in 0..3, global chunk 4s+quad at slot ^(R&7)
  int baseA[4], baseB[4], r7A[4], r7B[4];
#pragma unroll
  for (int t = 0; t < 4; ++t) {
    const int Ra = wm + t * 16 + l16;
    const int Rb = wn + t * 16 + l16;
    baseA[t] = Ra * 128; r7A[t] = Ra & 7;
    baseB[t] = Rb * 128; r7B[t] = Rb & 7;
  }

  floatx4 acc[4][4] = {};

  for (int k0 = 0; k0 < KS; k0 += BK) {
    __syncthreads();
#pragma unroll
    for (int j = 0; j < 8; ++j) {
      load16(P + gA[j] + k0,  As + lb[j]);
      load16(Vt + gB[j] + k0, Bs + lb[j]);
    }
    __syncthreads();

#pragma unroll
    for (int s = 0; s < 4; ++s) {
      short8 af[4], bf[4];
#pragma unroll
      for (int t = 0; t < 4; ++t) {
        af[t] = *reinterpret_cast<const short8*>(
            As + baseA[t] + (((4 * s + quad) ^ r7A[t]) * 8));
        bf[t] = *reinterpret_cast<const short8*>(
            Bs + baseB[t] + (((4 * s + quad) ^ r7B[t]) * 8));
      }
#pragma unroll
      for (int mt = 0; mt < 4; ++mt)
#pragma unroll
        for (int nt = 0; nt < 4; ++nt)
          acc[mt][nt] = __builtin_amdgcn_mfma_f32_16x16x32_bf16(
              af[mt], bf[nt], acc[mt][nt], 0, 0, 0);
    }
  }

  float* C = Osl + (size_t)blockIdx.z * S_SEQ * D_OUT;
#pragma unroll
  for (int mt = 0; mt < 4; ++mt)
#pragma unroll
    for (int nt = 0; nt < 4; ++nt) {
      const int row = bm + wm + mt * 16 + quad * 4;
      const int col = bn + wn + nt * 16 + l16;
#pragma unroll
      for (int r = 0; r < 4; ++r)
        C[(size_t)(row + r) * D_OUT + col] = acc[mt][nt][r];
    }
}

// ---------------- split-K reduce: O = s0+s1+s2+s3 ----------------
__global__ void add4_kernel(const float* __restrict__ s,
                            float* __restrict__ o, int n4) {
  int i = blockIdx.x * blockDim.x + threadIdx.x;
  if (i >= n4) return;
  const float4* s4 = reinterpret_cast<const float4*>(s);
  float4 x = s4[i];
  float4 y = s4[i + n4];
  float4 z = s4[i + 2 * n4];
  float4 w = s4[i + 3 * n4];
  x.x += y.x + z.x + w.x;
  x.y += y.y + z.y + w.y;
  x.z += y.z + z.z + w.z;
  x.w += y.w + z.w + w.w;
  reinterpret_cast<float4*>(o)[i] = x;
}

// ---------------- single-pass softmax (block per row, fp32 input) ----------
__global__ __launch_bounds__(256)
void softmax_kernel(const float* __restrict__ S, u16* __restrict__ P) {
  const int row = blockIdx.x, tid = threadIdx.x;
  const int lane = tid & 63, wave = tid >> 6;
  __shared__ float red[4];
  const float4* src = reinterpret_cast<const float4*>(S + (size_t)row * S_SEQ);
  ushort4* dst = reinterpret_cast<ushort4*>(P + (size_t)row * S_SEQ);

  float4 v[4];
  float m = -INFINITY;
#pragma unroll
  for (int t = 0; t < 4; ++t) {
    v[t] = src[tid + t * 256];
    m = fmaxf(m, fmaxf(fmaxf(v[t].x, v[t].y), fmaxf(v[t].z, v[t].w)));
  }
#pragma unroll
  for (int off = 1; off < 64; off <<= 1) m = fmaxf(m, __shfl_xor(m, off));
  if (lane == 0) red[wave] = m;
  __syncthreads();
  m = fmaxf(fmaxf(red[0], red[1]), fmaxf(red[2], red[3]));

  float e[16];
  float l = 0.f;
#pragma unroll
  for (int t = 0; t < 4; ++t) {
    e[4 * t + 0] = __expf(v[t].x - m);
    e[4 * t + 1] = __expf(v[t].y - m);
    e[4 * t + 2] = __expf(v[t].z - m);
    e[4 * t + 3] = __expf(v[t].w - m);
    l += e[4 * t + 0] + e[4 * t + 1] + e[4 * t + 2] + e[4 * t + 3];
  }
#pragma unroll
  for (int off = 1; off < 64; off <<= 1) l += __shfl_xor(l, off);
  __syncthreads();
  if (lane == 0) red[wave] = l;
  __syncthreads();
  const float li = 1.f / (red[0] + red[1] + red[2] + red[3]);

#pragma unroll
  for (int t = 0; t < 4; ++t) {
    ushort4 o;
    o.x = f2b(e[4 * t + 0] * li);
    o.y = f2b(e[4 * t + 1] * li);
    o.z = f2b(e[4 * t + 2] * li);
    o.w = f2b(e[4 * t + 3] * li);
    dst[tid + t * 256] = o;
  }
}

// ---------------- launcher ----------------
// ws (136 MB):
//  [0,8M) Xh  [8,16M) Xl  [16,22M) WtH[3072][1024]  [22,26M) WtL[2048][1024]
//  [0,32M)  P (overlays X/W after projections)
//  [32,36) Qa  [36,40) Qb  [40,44) Ka  [44,48) Kb   (int8 planes)
//  [64,72) Vt[1024][4096] bf16
//  [72,136) Ss fp32 [4096][4096]; PV O-slices 4x16MB overlay Ss (dead post-softmax)

extern "C" void kernel_launch(void* const* d_in, const int* in_sizes, int n_in,
                              void* d_out, int out_size, void* d_ws, size_t ws_size,
                              hipStream_t stream) {
  const float* X  = (const float*)d_in[0];
  const float* Wq = (const float*)d_in[1];
  const float* Wk = (const float*)d_in[2];
  const float* Wv = (const float*)d_in[3];
  float* O = (float*)d_out;
  char* ws = (char*)d_ws;

  const size_t MB = 1u << 20;
  u16*   Xh  = (u16*)(ws);
  u16*   Xl  = (u16*)(ws + 8 * MB);
  u16*   WtH = (u16*)(ws + 16 * MB);
  u16*   WtL = (u16*)(ws + 22 * MB);
  u16*   P   = (u16*)(ws);
  char*  Qa  = (char*)(ws + 32 * MB);
  char*  Qb  = (char*)(ws + 36 * MB);
  char*  Ka  = (char*)(ws + 40 * MB);
  char*  Kb  = (char*)(ws + 44 * MB);
  u16*   Vt  = (u16*)(ws + 64 * MB);
  float* Ss  = (float*)(ws + 72 * MB);
  float* Osl = (float*)(ws + 72 * MB);   // 4 x 16MB slices, overlays dead Ss

  // phase A: conversions
  split_bf16_kernel<<<(S_SEQ * D_IN / 4 + 255) / 256, 256, 0, stream>>>(
      X, Xh, Xl, S_SEQ * D_IN / 4);
  transpose_w_kernel<<<dim3(32, 32, 3), dim3(32, 8), 0, stream>>>(
      Wq, Wk, Wv, WtH, WtL);

  // phase B: merged QKV projection (768 blocks)
  qkv_kernel<<<dim3(3072 / 128, S_SEQ / 128), 256, 0, stream>>>(
      Xh, Xl, WtH, WtL, Qa, Qb, Ka, Kb, Vt);

  // phase B2: S = QK^T/32 fp32, i8 MFMA (2048 blocks, 128x64 tile, BK=128)
  s_i8_kernel<<<dim3(S_SEQ / 64, S_SEQ / 128), 256, 0, stream>>>(
      Qa, Qb, Ka, Kb, Ss);

  // phase C: single-pass softmax
  softmax_kernel<<<S_SEQ, 256, 0, stream>>>(Ss, P);

  // phase D: O-slices = P.V per K-quarter (x=bn XCD-local, BK=128), then add4
  pv_kernel<<<dim3(D_OUT / 128, S_SEQ / 128, 4), 256, 0, stream>>>(P, Vt, Osl);
  add4_kernel<<<(S_SEQ * D_OUT / 4 + 255) / 256, 256, 0, stream>>>(
      Osl, O, S_SEQ * D_OUT / 4);
}

// Round 11
// 270.187 us; speedup vs baseline: 1.1454x; 1.0278x over previous
//
#include <hip/hip_runtime.h>
#include <hip/hip_bf16.h>
#include <cstdint>
#include <type_traits>

// SingleHeadAttention. Numerics (validated r2-r10, absmax 1.0):
//   Q/K proj: 3-term split-bf16 MFMA; Q,K quantized int16-fixed (q=a*256+b);
//   S = (H<<16+M<<8+L)*2^-21 exact -> fp32 (i16-S clamps! r6); V/P/PV bf16.
// r11: PV reduction-traffic attack. r10 K-loop is validated (FETCH ideal,
//   conflicts 0); the untouched cost is 144MB of split-K reduce traffic
//   (64 fp32 write + 64 read + 16 write ~ 23us at HBM BW). Now: split-K 2
//   (512 blocks = exactly 2/CU, one residency round), bf16 O-slices
//   (|slice| <= ~90, RNE err <=0.18/slice -> absmax +~0.1-0.4), add2 pass.
//   Epilogue traffic 144 -> 48MB. Conversions merged into one launch.

using u16 = unsigned short;
typedef __attribute__((ext_vector_type(8))) short short8;
typedef __attribute__((ext_vector_type(4))) float floatx4;
typedef __attribute__((ext_vector_type(4))) int intx4;

static constexpr int S_SEQ = 4096;
static constexpr int D_IN  = 1024;
static constexpr int D_OUT = 1024;

__device__ __forceinline__ u16 f2b(float f) {
  uint32_t u = __builtin_bit_cast(uint32_t, f);
  u = (u + 0x7FFFu + ((u >> 16) & 1u)) >> 16;
  return (u16)u;
}
__device__ __forceinline__ float b2f(u16 b) {
  return __builtin_bit_cast(float, (uint32_t)b << 16);
}
__device__ __forceinline__ void load16(const void* g, void* l) {
  __builtin_amdgcn_global_load_lds(
      (const __attribute__((address_space(1))) void*)g,
      (__attribute__((address_space(3))) void*)l,
      16, 0, 0);
}

// ---------------- merged conversions ----------------
// z<3: transpose W[z] -> WtH(+WtL for z<2), 32x32 tiles (x<32 only).
// z=3: elementwise split of X (all 128x32 blocks).
__global__ void convert_kernel(const float* __restrict__ X,
                               const float* __restrict__ Wq,
                               const float* __restrict__ Wk,
                               const float* __restrict__ Wv,
                               u16* __restrict__ Xh, u16* __restrict__ Xl,
                               u16* __restrict__ WtH, u16* __restrict__ WtL) {
  const int z = blockIdx.z;
  const int tx = threadIdx.x, ty = threadIdx.y;   // block (32,8)
  if (z == 3) {                                   // X split, float4 per thread
    const int bid = blockIdx.y * 128 + blockIdx.x;
    const int i = bid * 256 + ty * 32 + tx;       // < 1M float4s
    float4 v = reinterpret_cast<const float4*>(X)[i];
    ushort4 h, l;
    h.x = f2b(v.x); l.x = f2b(v.x - b2f(h.x));
    h.y = f2b(v.y); l.y = f2b(v.y - b2f(h.y));
    h.z = f2b(v.z); l.z = f2b(v.z - b2f(h.z));
    h.w = f2b(v.w); l.w = f2b(v.w - b2f(h.w));
    reinterpret_cast<ushort4*>(Xh)[i] = h;
    reinterpret_cast<ushort4*>(Xl)[i] = l;
    return;
  }
  if (blockIdx.x >= 32) return;                   // W grids are 32x32
  const float* src = (z == 0) ? Wq : (z == 1) ? Wk : Wv;
  u16* dH = WtH + (size_t)z * 1024 * 1024;
  u16* dL = (z < 2) ? WtL + (size_t)z * 1024 * 1024 : nullptr;
  __shared__ float tile[32][33];
  int bx = blockIdx.x * 32, by = blockIdx.y * 32;
  for (int j = 0; j < 32; j += 8)
    tile[ty + j][tx] = src[(size_t)(by + ty + j) * 1024 + bx + tx];
  __syncthreads();
  for (int j = 0; j < 32; j += 8) {
    float v = tile[tx][ty + j];
    u16 h = f2b(v);
    size_t idx = (size_t)(bx + ty + j) * 1024 + by + tx;
    dH[idx] = h;
    if (dL) dL[idx] = f2b(v - b2f(h));
  }
}

// ---------------- merged QKV projection (split-bf16 compute) ----------------
__global__ __launch_bounds__(256)
void qkv_kernel(const u16* __restrict__ Xh, const u16* __restrict__ Xl,
                const u16* __restrict__ WtH, const u16* __restrict__ WtL,
                char* __restrict__ Qa, char* __restrict__ Qb,
                char* __restrict__ Ka, char* __restrict__ Kb,
                u16* __restrict__ Vt) {
  constexpr int BK = 32, K = D_IN;
  constexpr int TILE = 128 * BK;
  __shared__ __align__(16) u16 smem[4 * TILE];
  u16* AsH = smem;
  u16* BsH = smem + TILE;
  u16* AsL = smem + 2 * TILE;
  u16* BsL = smem + 3 * TILE;

  const int tid  = threadIdx.x;
  const int wave = tid >> 6;
  const int lane = tid & 63;
  const int bm   = blockIdx.y * 128;
  const int bn   = blockIdx.x * 128;     // [0,3072)
  const bool splitB = bn < 2048;
  const int wm   = (wave >> 1) * 64;
  const int wn   = (wave & 1) * 64;
  const int quad = lane >> 4;
  const int l16  = lane & 15;

  const int srow = wave * 16 + (lane >> 2);
  const int scol = (lane & 3) * 8;
  const size_t offA = (size_t)(bm + srow) * K + scol;
  const size_t offB = (size_t)(bn + srow) * K + scol;
  const size_t off64 = (size_t)64 * K;
  const int lds0 = wave * 512;
  const int lds1 = 2048 + wave * 512;

  floatx4 acc[4][4] = {};

  for (int k0 = 0; k0 < K; k0 += BK) {
    __syncthreads();
    load16(Xh + offA + k0,          AsH + lds0);
    load16(Xh + offA + off64 + k0,  AsH + lds1);
    load16(WtH + offB + k0,         BsH + lds0);
    load16(WtH + offB + off64 + k0, BsH + lds1);
    if (splitB) {
      load16(Xl + offA + k0,          AsL + lds0);
      load16(Xl + offA + off64 + k0,  AsL + lds1);
      load16(WtL + offB + k0,         BsL + lds0);
      load16(WtL + offB + off64 + k0, BsL + lds1);
    }
    __syncthreads();

    short8 ah[4], bh[4], al[4], bl[4];
#pragma unroll
    for (int t = 0; t < 4; ++t) {
      ah[t] = *reinterpret_cast<const short8*>(AsH + (wm + t * 16 + l16) * BK + quad * 8);
      bh[t] = *reinterpret_cast<const short8*>(BsH + (wn + t * 16 + l16) * BK + quad * 8);
    }
    if (splitB) {
#pragma unroll
      for (int t = 0; t < 4; ++t) {
        al[t] = *reinterpret_cast<const short8*>(AsL + (wm + t * 16 + l16) * BK + quad * 8);
        bl[t] = *reinterpret_cast<const short8*>(BsL + (wn + t * 16 + l16) * BK + quad * 8);
      }
    }

#pragma unroll
    for (int mt = 0; mt < 4; ++mt)
#pragma unroll
      for (int nt = 0; nt < 4; ++nt)
        acc[mt][nt] = __builtin_amdgcn_mfma_f32_16x16x32_bf16(
            ah[mt], bh[nt], acc[mt][nt], 0, 0, 0);
    if (splitB) {
#pragma unroll
      for (int mt = 0; mt < 4; ++mt)
#pragma unroll
        for (int nt = 0; nt < 4; ++nt) {
          acc[mt][nt] = __builtin_amdgcn_mfma_f32_16x16x32_bf16(
              ah[mt], bl[nt], acc[mt][nt], 0, 0, 0);
          acc[mt][nt] = __builtin_amdgcn_mfma_f32_16x16x32_bf16(
              al[mt], bh[nt], acc[mt][nt], 0, 0, 0);
        }
    }
  }

  // epilogue (C/D: col=lane&15, row=quad*4+reg)
#pragma unroll
  for (int mt = 0; mt < 4; ++mt) {
#pragma unroll
    for (int nt = 0; nt < 4; ++nt) {
      const int row = bm + wm + mt * 16 + quad * 4;
      const int col = bn + wn + nt * 16 + l16;
      if (bn < 2048) {                 // Q or K -> int16-fixed byte planes
        char* Pa = (bn < 1024) ? Qa : Ka;
        char* Pb = (bn < 1024) ? Qb : Kb;
        const int c = (bn < 1024) ? col : col - 1024;
#pragma unroll
        for (int r = 0; r < 4; ++r) {
          float v = acc[mt][nt][r];
          int q16 = (int)rintf(v * 256.f);
          q16 = min(max(q16, -32512), 32512);    // |Q| <= 127 (6.9 sigma)
          int a = (q16 + 128) >> 8;              // a in [-127,127]
          int b = q16 - (a << 8);                // b in [-128,127]
          size_t idx = (size_t)(row + r) * 1024 + c;
          Pa[idx] = (char)a;
          Pb[idx] = (char)b;
        }
      } else {                         // V, write transposed, packed 8B store
        ushort4 o;
        o.x = f2b(acc[mt][nt][0]);
        o.y = f2b(acc[mt][nt][1]);
        o.z = f2b(acc[mt][nt][2]);
        o.w = f2b(acc[mt][nt][3]);
        *reinterpret_cast<ushort4*>(Vt + (size_t)(col - 2048) * S_SEQ + row) = o;
      }
    }
  }
}

// ---------------- i8 fixed-point S GEMM ----------------
// S[m][n] = (H<<16 + M<<8 + L) * 2^-21  (fp32; exact int recombine)
// Tile 128x64, BK=128 bytes, 8 iters. LDS rows 128B = 8 chunks of 16B;
// chunk g of row R stored at slot g^(R&7) -> balanced b128 frag reads.
__global__ __launch_bounds__(256)
void s_i8_kernel(const char* __restrict__ Qa, const char* __restrict__ Qb,
                 const char* __restrict__ Ka, const char* __restrict__ Kb,
                 float* __restrict__ S) {
  constexpr int K = D_IN, BK = 128;
  __shared__ __align__(16) char smem[48 * 1024];
  char* QaS = smem;                // [128][128]
  char* QbS = smem + 16384;        // [128][128]
  char* KaS = smem + 32768;        // [64][128]
  char* KbS = smem + 40960;        // [64][128]

  const int tid  = threadIdx.x;
  const int wave = tid >> 6;
  const int lane = tid & 63;
  const int bm   = blockIdx.y * 128;
  const int bn   = blockIdx.x * 64;
  const int wm   = (wave >> 1) * 64;
  const int wn   = (wave & 1) * 32;
  const int quad = lane >> 4;
  const int l16  = lane & 15;

  // staging: 8 rows x 128B per wave-issue; lane -> (row=srow, chunk=(lane&7)^srow)
  const int srow = lane >> 3;                 // 0..7
  const int scol = ((lane & 7) ^ srow) * 16;  // XOR swizzle
  int gQ[4], gK[2];
#pragma unroll
  for (int j = 0; j < 4; ++j)
    gQ[j] = (bm + j * 32 + wave * 8 + srow) * K + scol;
#pragma unroll
  for (int j = 0; j < 2; ++j)
    gK[j] = (bn + j * 32 + wave * 8 + srow) * K + scol;
  const int lQ[4] = {(0 * 32 + wave * 8) * 128, (1 * 32 + wave * 8) * 128,
                     (2 * 32 + wave * 8) * 128, (3 * 32 + wave * 8) * 128};
  const int lK[2] = {(0 * 32 + wave * 8) * 128, (1 * 32 + wave * 8) * 128};

  // frag reads: row R, global chunk g=quad+4s at slot (g^(R&7))
  const int r7 = l16 & 7;
  int cA[4], cB[2];
#pragma unroll
  for (int t = 0; t < 4; ++t)
    cA[t] = (wm + t * 16 + l16) * 128 + ((quad ^ r7) * 16);
#pragma unroll
  for (int t = 0; t < 2; ++t)
    cB[t] = (wn + t * 16 + l16) * 128 + ((quad ^ r7) * 16);

  intx4 accH[4][2] = {};
  intx4 accM[4][2] = {};
  intx4 accL[4][2] = {};

  for (int k0 = 0; k0 < K; k0 += BK) {
    __syncthreads();
#pragma unroll
    for (int j = 0; j < 4; ++j) {
      load16(Qa + gQ[j] + k0, QaS + lQ[j]);
      load16(Qb + gQ[j] + k0, QbS + lQ[j]);
    }
#pragma unroll
    for (int j = 0; j < 2; ++j) {
      load16(Ka + gK[j] + k0, KaS + lK[j]);
      load16(Kb + gK[j] + k0, KbS + lK[j]);
    }
    __syncthreads();

#pragma unroll
    for (int s = 0; s < 2; ++s) {
      const int so = s * 64;
      intx4 ah[4], al[4];
#pragma unroll
      for (int t = 0; t < 4; ++t) {
        ah[t] = *reinterpret_cast<const intx4*>(QaS + (cA[t] ^ so));
        al[t] = *reinterpret_cast<const intx4*>(QbS + (cA[t] ^ so));
      }
#pragma unroll
      for (int nt = 0; nt < 2; ++nt) {
        intx4 bh = *reinterpret_cast<const intx4*>(KaS + (cB[nt] ^ so));
#pragma unroll
        for (int mt = 0; mt < 4; ++mt) {
          accH[mt][nt] = __builtin_amdgcn_mfma_i32_16x16x64_i8(ah[mt], bh, accH[mt][nt], 0, 0, 0);
          accM[mt][nt] = __builtin_amdgcn_mfma_i32_16x16x64_i8(al[mt], bh, accM[mt][nt], 0, 0, 0);
        }
        intx4 bl = *reinterpret_cast<const intx4*>(KbS + (cB[nt] ^ so));
#pragma unroll
        for (int mt = 0; mt < 4; ++mt) {
          accM[mt][nt] = __builtin_amdgcn_mfma_i32_16x16x64_i8(ah[mt], bl, accM[mt][nt], 0, 0, 0);
          accL[mt][nt] = __builtin_amdgcn_mfma_i32_16x16x64_i8(al[mt], bl, accL[mt][nt], 0, 0, 0);
        }
      }
    }
  }

  // epilogue: exact int64 recombine -> fp32, scale 2^-16 (fixed^2) * 2^-5 (1/32)
  constexpr float SC = 4.76837158203125e-07f;
#pragma unroll
  for (int mt = 0; mt < 4; ++mt)
#pragma unroll
    for (int nt = 0; nt < 2; ++nt) {
      const int row = bm + wm + mt * 16 + quad * 4;
      const int col = bn + wn + nt * 16 + l16;
#pragma unroll
      for (int r = 0; r < 4; ++r) {
        long long fix = (((long long)accH[mt][nt][r]) << 16) +
                        (((long long)accM[mt][nt][r]) << 8) +
                        (long long)accL[mt][nt][r];
        S[(size_t)(row + r) * S_SEQ + col] = (float)fix * SC;
      }
    }
}

// ---------------- PV GEMM: Osl[z] = P(bf16).V over K-half z (bf16 out) ------
// Tile 128x128, BK=128 elems (256B LDS rows = 16 chunks of 16B; chunk g of
// row R at slot g^(R&7), bit 3 untouched -> balanced b128 reads).
// Grid (x=bn 8, y=bm 32, z=2): XCD = id%8 = bn -> this XCD's Vt slice (1MB)
// is L2-resident; P streams via the shared L3. Non-atomic bf16 slice writes.
__global__ __launch_bounds__(256)
void pv_kernel(const u16* __restrict__ P, const u16* __restrict__ Vt,
               u16* __restrict__ Osl) {
  constexpr int LDA = S_SEQ;          // row stride of P and Vt (elements)
  constexpr int KS  = S_SEQ / 2;      // 2048 per z-slice
  constexpr int BK  = 128;
  __shared__ __align__(16) u16 smem[2 * 128 * 128];   // 64 KB
  u16* As = smem;                     // P tile   [128][128] swizzled
  u16* Bs = smem + 128 * 128;         // Vt tile  [128][128] swizzled

  const int tid  = threadIdx.x;
  const int wave = tid >> 6;
  const int lane = tid & 63;
  const int bn   = blockIdx.x * 128;  // XCD-local (gridDim.x = 8)
  const int bm   = blockIdx.y * 128;
  const int kz   = blockIdx.z * KS;
  const int wm   = (wave >> 1) * 64;
  const int wn   = (wave & 1) * 64;
  const int quad = lane >> 4;
  const int l16  = lane & 15;

  // staging: each issue = 4 rows x 256B; lane -> (srow=lane>>4, pos=lane&15).
  // LDS slot pos of row R holds global chunk pos^(R&7); R&7 = 4*(wave&1)+srow.
  const int srow = lane >> 4;                       // 0..3
  const int r7s  = 4 * (wave & 1) + srow;
  const int gcol = ((lane & 15) ^ r7s) * 8;         // element offset in row
  int gA[8], gB[8], lb[8];
#pragma unroll
  for (int j = 0; j < 8; ++j) {
    const int row = j * 16 + wave * 4;              // rows row..row+3 (srow)
    gA[j] = (bm + row + srow) * LDA + kz + gcol;
    gB[j] = (bn + row + srow) * LDA + kz + gcol;
    lb[j] = row * 128;                              // u16 offset, +lane*8 by HW
  }

  // frag reads: row R, k-step s in 0..3, global chunk 4s+quad at slot ^(R&7)
  int baseA[4], baseB[4], r7A[4], r7B[4];
#pragma unroll
  for (int t = 0; t < 4; ++t) {
    const int Ra = wm + t * 16 + l16;
    const int Rb = wn + t * 16 + l16;
    baseA[t] = Ra * 128; r7A[t] = Ra & 7;
    baseB[t] = Rb * 128; r7B[t] = Rb & 7;
  }

  floatx4 acc[4][4] = {};

  for (int k0 = 0; k0 < KS; k0 += BK) {
    __syncthreads();
#pragma unroll
    for (int j = 0; j < 8; ++j) {
      load16(P + gA[j] + k0,  As + lb[j]);
      load16(Vt + gB[j] + k0, Bs + lb[j]);
    }
    __syncthreads();

#pragma unroll
    for (int s = 0; s < 4; ++s) {
      short8 af[4], bf[4];
#pragma unroll
      for (int t = 0; t < 4; ++t) {
        af[t] = *reinterpret_cast<const short8*>(
            As + baseA[t] + (((4 * s + quad) ^ r7A[t]) * 8));
        bf[t] = *reinterpret_cast<const short8*>(
            Bs + baseB[t] + (((4 * s + quad) ^ r7B[t]) * 8));
      }
#pragma unroll
      for (int mt = 0; mt < 4; ++mt)
#pragma unroll
        for (int nt = 0; nt < 4; ++nt)
          acc[mt][nt] = __builtin_amdgcn_mfma_f32_16x16x32_bf16(
              af[mt], bf[nt], acc[mt][nt], 0, 0, 0);
    }
  }

  u16* C = Osl + (size_t)blockIdx.z * S_SEQ * D_OUT;
#pragma unroll
  for (int mt = 0; mt < 4; ++mt)
#pragma unroll
    for (int nt = 0; nt < 4; ++nt) {
      const int row = bm + wm + mt * 16 + quad * 4;
      const int col = bn + wn + nt * 16 + l16;
#pragma unroll
      for (int r = 0; r < 4; ++r)
        C[(size_t)(row + r) * D_OUT + col] = f2b(acc[mt][nt][r]);
    }
}

// ---------------- split-K reduce: O = s0+s1 (bf16 slices -> fp32) ----------
__global__ void add2_kernel(const u16* __restrict__ s,
                            float* __restrict__ o, int n4) {
  int i = blockIdx.x * blockDim.x + threadIdx.x;
  if (i >= n4) return;
  ushort4 a = reinterpret_cast<const ushort4*>(s)[i];
  ushort4 b = reinterpret_cast<const ushort4*>(s)[i + n4];
  float4 x;
  x.x = b2f(a.x) + b2f(b.x);
  x.y = b2f(a.y) + b2f(b.y);
  x.z = b2f(a.z) + b2f(b.z);
  x.w = b2f(a.w) + b2f(b.w);
  reinterpret_cast<float4*>(o)[i] = x;
}

// ---------------- single-pass softmax (block per row, fp32 input) ----------
__global__ __launch_bounds__(256)
void softmax_kernel(const float* __restrict__ S, u16* __restrict__ P) {
  const int row = blockIdx.x, tid = threadIdx.x;
  const int lane = tid & 63, wave = tid >> 6;
  __shared__ float red[4];
  const float4* src = reinterpret_cast<const float4*>(S + (size_t)row * S_SEQ);
  ushort4* dst = reinterpret_cast<ushort4*>(P + (size_t)row * S_SEQ);

  float4 v[4];
  float m = -INFINITY;
#pragma unroll
  for (int t = 0; t < 4; ++t) {
    v[t] = src[tid + t * 256];
    m = fmaxf(m, fmaxf(fmaxf(v[t].x, v[t].y), fmaxf(v[t].z, v[t].w)));
  }
#pragma unroll
  for (int off = 1; off < 64; off <<= 1) m = fmaxf(m, __shfl_xor(m, off));
  if (lane == 0) red[wave] = m;
  __syncthreads();
  m = fmaxf(fmaxf(red[0], red[1]), fmaxf(red[2], red[3]));

  float e[16];
  float l = 0.f;
#pragma unroll
  for (int t = 0; t < 4; ++t) {
    e[4 * t + 0] = __expf(v[t].x - m);
    e[4 * t + 1] = __expf(v[t].y - m);
    e[4 * t + 2] = __expf(v[t].z - m);
    e[4 * t + 3] = __expf(v[t].w - m);
    l += e[4 * t + 0] + e[4 * t + 1] + e[4 * t + 2] + e[4 * t + 3];
  }
#pragma unroll
  for (int off = 1; off < 64; off <<= 1) l += __shfl_xor(l, off);
  __syncthreads();
  if (lane == 0) red[wave] = l;
  __syncthreads();
  const float li = 1.f / (red[0] + red[1] + red[2] + red[3]);

#pragma unroll
  for (int t = 0; t < 4; ++t) {
    ushort4 o;
    o.x = f2b(e[4 * t + 0] * li);
    o.y = f2b(e[4 * t + 1] * li);
    o.z = f2b(e[4 * t + 2] * li);
    o.w = f2b(e[4 * t + 3] * li);
    dst[tid + t * 256] = o;
  }
}

// ---------------- launcher ----------------
// ws (136 MB):
//  [0,8M) Xh  [8,16M) Xl  [16,22M) WtH[3072][1024]  [22,26M) WtL[2048][1024]
//  [0,32M)  P (overlays X/W after projections)
//  [32,36) Qa  [36,40) Qb  [40,44) Ka  [44,48) Kb   (int8 planes)
//  [64,72) Vt[1024][4096] bf16
//  [72,136) Ss fp32 [4096][4096]; PV bf16 O-slices 2x8MB overlay Ss (dead)

extern "C" void kernel_launch(void* const* d_in, const int* in_sizes, int n_in,
                              void* d_out, int out_size, void* d_ws, size_t ws_size,
                              hipStream_t stream) {
  const float* X  = (const float*)d_in[0];
  const float* Wq = (const float*)d_in[1];
  const float* Wk = (const float*)d_in[2];
  const float* Wv = (const float*)d_in[3];
  float* O = (float*)d_out;
  char* ws = (char*)d_ws;

  const size_t MB = 1u << 20;
  u16*   Xh  = (u16*)(ws);
  u16*   Xl  = (u16*)(ws + 8 * MB);
  u16*   WtH = (u16*)(ws + 16 * MB);
  u16*   WtL = (u16*)(ws + 22 * MB);
  u16*   P   = (u16*)(ws);
  char*  Qa  = (char*)(ws + 32 * MB);
  char*  Qb  = (char*)(ws + 36 * MB);
  char*  Ka  = (char*)(ws + 40 * MB);
  char*  Kb  = (char*)(ws + 44 * MB);
  u16*   Vt  = (u16*)(ws + 64 * MB);
  float* Ss  = (float*)(ws + 72 * MB);
  u16*   Osl = (u16*)(ws + 72 * MB);    // 2 x 8MB bf16 slices, overlay dead Ss

  // phase A: conversions (one launch; z<3 = W transposes, z=3 = X split)
  convert_kernel<<<dim3(128, 32, 4), dim3(32, 8), 0, stream>>>(
      X, Wq, Wk, Wv, Xh, Xl, WtH, WtL);

  // phase B: merged QKV projection (768 blocks)
  qkv_kernel<<<dim3(3072 / 128, S_SEQ / 128), 256, 0, stream>>>(
      Xh, Xl, WtH, WtL, Qa, Qb, Ka, Kb, Vt);

  // phase B2: S = QK^T/32 fp32, i8 MFMA (2048 blocks, 128x64 tile, BK=128)
  s_i8_kernel<<<dim3(S_SEQ / 64, S_SEQ / 128), 256, 0, stream>>>(
      Qa, Qb, Ka, Kb, Ss);

  // phase C: single-pass softmax
  softmax_kernel<<<S_SEQ, 256, 0, stream>>>(Ss, P);

  // phase D: bf16 O-slices = P.V per K-half (512 blocks = 2/CU), then add2
  pv_kernel<<<dim3(D_OUT / 128, S_SEQ / 128, 2), 256, 0, stream>>>(P, Vt, Osl);
  add2_kernel<<<(S_SEQ * D_OUT / 4 + 255) / 256, 256, 0, stream>>>(
      Osl, O, S_SEQ * D_OUT / 4);
}